// Round 3
// baseline (113.521 us; speedup 1.0000x reference)
//
#include <hip/hip_runtime.h>
#include <hip/hip_bf16.h>

typedef __attribute__((ext_vector_type(4))) float f32x4;
typedef __attribute__((ext_vector_type(8))) short s16x8;

#define MFMA16(a, b, c) __builtin_amdgcn_mfma_f32_16x16x32_bf16(a, b, c, 0, 0, 0)

// elements per Q/K/V plane: 32 n * 12544 u * 32 d  (== row-major [100352][128])
#define PLANE ((size_t)12845056)
#define QSCALE 0.17677669529663687f

__device__ __forceinline__ unsigned short f2bf(float f) {
  union { float f; unsigned u; } v; v.f = f;
  unsigned u = v.u;
  u += 0x7fff + ((u >> 16) & 1);   // RNE
  return (unsigned short)(u >> 16);
}
__device__ __forceinline__ float bf2f(unsigned short h) {
  union { unsigned u; float f; } v; v.u = ((unsigned)h) << 16;
  return v.f;
}

typedef const __attribute__((address_space(1))) char gas_char;
typedef __attribute__((address_space(3))) char las_char;
__device__ __forceinline__ void gload_lds16(const void* g, void* l) {
  __builtin_amdgcn_global_load_lds((gas_char*)g, (las_char*)l, 16, 0, 0);
}

// ---------------------------------------------------------------------------
// Prepass: W2[s][c2][k] bf16 linear (Q-part pre-scaled), W3[c][k] bf16 linear,
// BIASA[cl][ij][lane][4] = bias+masks in MFMA C-operand layout.
// ---------------------------------------------------------------------------
__global__ void k_prep(const float* __restrict__ QW, const float* __restrict__ OW,
                       const float* __restrict__ RPE,
                       unsigned short* __restrict__ W2, unsigned short* __restrict__ W3,
                       float* __restrict__ BIASA) {
  const int b = blockIdx.x, t = threadIdx.x;
  if (b < 24) {                       // qkv_w: 3*128*128, linear [s][c2][k]
    const int e = (b * 256 + t) * 8;
    const int s = e >> 14;
    const int c2 = (e & 16383) >> 7;
    const int k0 = e & 127;
    const float sf = (s == 0) ? QSCALE : 1.0f;
    const float* src = QW + (size_t)(c2 * 3 + s) * 128 + k0;
#pragma unroll
    for (int q = 0; q < 8; ++q) W2[e + q] = f2bf(src[q] * sf);
  } else if (b < 32) {                // out_w: 128*128 linear
    const int e = ((b - 24) * 256 + t) * 8;
#pragma unroll
    for (int q = 0; q < 8; ++q) W3[e + q] = f2bf(OW[e + q]);
  } else {                            // bias tables in acc-fragment layout
    const int cl = b - 32;
    const int rm = cl >> 1, cm = cl & 1;
    for (int w = 0; w < 16; ++w) {
      const int idx = w * 256 + t;       // ((i*4+j)*64 + lane)*4 + rr
      const int rr = idx & 3;
      const int lane = (idx >> 2) & 63;
      const int ij = idx >> 8;
      const int q = (ij >> 2) * 16 + (lane >> 4) * 4 + rr;
      const int k = (ij & 3) * 16 + (lane & 15);
      float v;
      if (q >= 49 || k >= 49) v = -1.0e30f;
      else {
        const int xq = q / 7, yq = q - xq * 7;
        const int xk = k / 7, yk = k - xk * 7;
        v = RPE[(xk - xq + 6) * 13 + (yk - yq + 6)];
        if (rm && ((xq >= 4) != (xk >= 4))) v = -1.0e30f;
        if (cm && (((yq == 4) && (yk < 4)) || ((yq < 4) && (yk >= 4)))) v = -1.0e30f;
      }
      BIASA[cl * 4096 + idx] = v;
    }
  }
}

// ---------------------------------------------------------------------------
// GEMM1: 64x128 tile, A-only LDS (16KB), B-frags direct from L2-hot W2,
// all 3 s per block with A-frags cached in VGPR, C staged through A-LDS.
// ---------------------------------------------------------------------------
__global__ __launch_bounds__(256, 4)
void k_gemm_qkv(const float* __restrict__ X, const unsigned short* __restrict__ W2,
                const float* __restrict__ B, unsigned short* __restrict__ OUT) {
  __shared__ unsigned short Alds[64 * 128];   // 16KB
  const int tid = threadIdx.x;
  const int bm = blockIdx.x;                  // 0..1567

  // stage A: 4 threads per row, fp32 -> bf16, XOR-swizzled rows
  {
    const int rr = tid >> 2;
    const int qk = tid & 3;
    const int row = bm * 64 + rr;
    const int n = row / 3136;
    const int p = row - n * 3136;
    const int r_ = p / 56, c_ = p - r_ * 56;
    int ro = r_ + 4; if (ro >= 56) ro -= 56;   // roll(-4)
    int co = c_ + 4; if (co >= 56) co -= 56;
    const float* src = X + (((size_t)n * 3136 + ro * 56 + co) << 7) + qk * 32;
    char* arow = (char*)Alds + rr * 256;
#pragma unroll
    for (int g = 0; g < 4; ++g) {
      const f32x4 v0 = *(const f32x4*)(src + g * 8);
      const f32x4 v1 = *(const f32x4*)(src + g * 8 + 4);
      s16x8 h;
      h[0] = (short)f2bf(v0.x); h[1] = (short)f2bf(v0.y);
      h[2] = (short)f2bf(v0.z); h[3] = (short)f2bf(v0.w);
      h[4] = (short)f2bf(v1.x); h[5] = (short)f2bf(v1.y);
      h[6] = (short)f2bf(v1.z); h[7] = (short)f2bf(v1.w);
      *(s16x8*)(arow + ((qk * 64 + g * 16) ^ ((rr & 7) << 4))) = h;
    }
  }
  __syncthreads();

  const int lane = tid & 63, wid = tid >> 6;
  const int li = lane & 15, hi = lane >> 4;
  const int rw = (wid >> 1) << 5;   // 0 or 32
  const int cw = (wid & 1) << 6;    // 0 or 64

  // A fragments cached across all 3 s-passes
  s16x8 af[4][2];
#pragma unroll
  for (int kc = 0; kc < 4; ++kc)
#pragma unroll
    for (int i = 0; i < 2; ++i) {
      const int ra = rw + i * 16 + li;
      af[kc][i] = *(const s16x8*)((const char*)Alds + ra * 256 + ((kc * 64 + hi * 16) ^ ((ra & 7) << 4)));
    }
  __syncthreads();   // Alds free for C staging

  const size_t outbase = (size_t)bm * 8192;   // block's contiguous C region (elems)

  for (int s = 0; s < 3; ++s) {
    f32x4 acc[2][4];
#pragma unroll
    for (int i = 0; i < 2; ++i)
#pragma unroll
      for (int j = 0; j < 4; ++j) acc[i][j] = (f32x4){0.f, 0.f, 0.f, 0.f};

    const unsigned short* W2s = W2 + (size_t)s * 16384;
#pragma unroll
    for (int kc = 0; kc < 4; ++kc) {
      s16x8 bfr[4];
#pragma unroll
      for (int j = 0; j < 4; ++j)
        bfr[j] = *(const s16x8*)(W2s + (cw + j * 16 + li) * 128 + kc * 32 + hi * 8);
#pragma unroll
      for (int i = 0; i < 2; ++i)
#pragma unroll
        for (int j = 0; j < 4; ++j)
          acc[i][j] = MFMA16(af[kc][i], bfr[j], acc[i][j]);
    }

    const float bsf = (s == 0) ? QSCALE : 1.0f;
    float bias4[4];
#pragma unroll
    for (int j = 0; j < 4; ++j) bias4[j] = B[(cw + j * 16 + li) * 3 + s] * bsf;

    // C -> LDS (swizzled), then linear coalesced stores
#pragma unroll
    for (int i = 0; i < 2; ++i)
#pragma unroll
      for (int r = 0; r < 4; ++r) {
        const int rowC = rw + i * 16 + hi * 4 + r;
#pragma unroll
        for (int j = 0; j < 4; ++j) {
          const int e = cw + j * 16 + li;
          *(unsigned short*)((char*)Alds + rowC * 256 + ((e * 2) ^ ((rowC & 7) << 4))) =
              f2bf(acc[i][j][r] + bias4[j]);
        }
      }
    __syncthreads();

    unsigned short* outS = OUT + (size_t)s * PLANE + outbase;
#pragma unroll
    for (int c = 0; c < 4; ++c) {
      const int ofs = c * 4096 + tid * 16;
      const int rowL = ofs >> 8, colb = ofs & 255;
      const s16x8 v = *(const s16x8*)((const char*)Alds + rowL * 256 + (colb ^ ((rowL & 7) << 4)));
      *(s16x8*)((char*)outS + ofs) = v;
    }
    if (s < 2) __syncthreads();
  }
}

// ---------------------------------------------------------------------------
// Attention: 1 wave per group; bias via MFMA C-in fragments; P + O through
// small swizzled LDS; coalesced O stores.
// ---------------------------------------------------------------------------
__global__ __launch_bounds__(64, 4)
void k_attn(const unsigned short* __restrict__ QKV, const float* __restrict__ BIASA,
            unsigned short* __restrict__ AOUT) {
  __shared__ unsigned short P[64 * 64];    // 8KB, swizzled rows of 128B
  __shared__ unsigned short Olds[64 * 32]; // 4KB, swizzled rows of 64B

  const int lane = threadIdx.x;
  const int blk = blockIdx.x;
  const int n = blk >> 8;
  const int rem = blk & 255;
  const int wh = (rem >> 3) & 7;
  const int ww = rem & 7;
  const size_t rowbase = ((size_t)(n * 12544 + rem * 49)) << 5;
  const unsigned short* qp = QKV + rowbase;
  const unsigned short* kp = qp + PLANE;
  const unsigned short* vp = kp + PLANE;
  const int cl = (wh == 7 ? 2 : 0) + (ww == 7 ? 1 : 0);
  const f32x4* bptr = (const f32x4*)(BIASA + (size_t)cl * 4096) + lane;

  const int li = lane & 15, hi = lane >> 4;

  s16x8 qf[4], kf[4];
#pragma unroll
  for (int i = 0; i < 4; ++i) {
    qf[i] = *(const s16x8*)(qp + (i * 16 + li) * 32 + hi * 8);
    kf[i] = *(const s16x8*)(kp + (i * 16 + li) * 32 + hi * 8);
  }

  f32x4 sc[4][4];
#pragma unroll
  for (int i = 0; i < 4; ++i)
#pragma unroll
    for (int j = 0; j < 4; ++j) sc[i][j] = bptr[(i * 4 + j) * 64];
#pragma unroll
  for (int i = 0; i < 4; ++i)
#pragma unroll
    for (int j = 0; j < 4; ++j)
      sc[i][j] = MFMA16(qf[i], kf[j], sc[i][j]);   // logits incl. bias+mask

  float rinv[4][4];
#pragma unroll
  for (int i = 0; i < 4; ++i) {
#pragma unroll
    for (int r = 0; r < 4; ++r) {
      const int q = i * 16 + hi * 4 + r;
      float sum = 0.f;
      unsigned short pb[4];
#pragma unroll
      for (int j = 0; j < 4; ++j) {
        const unsigned short b = f2bf(__expf(sc[i][j][r]));
        pb[j] = b;
        sum += bf2f(b);
      }
#pragma unroll
      for (int d = 1; d < 16; d <<= 1) sum += __shfl_xor(sum, d);
      rinv[i][r] = 1.0f / sum;
#pragma unroll
      for (int j = 0; j < 4; ++j)
        *(unsigned short*)((char*)P + q * 128 + ((((j * 16 + li) * 2)) ^ ((q & 7) << 4))) = pb[j];
    }
  }

  // V B-fragments direct from global (L2/L3-hot)
  s16x8 vf[2][2];
#pragma unroll
  for (int kc = 0; kc < 2; ++kc)
#pragma unroll
    for (int fn = 0; fn < 2; ++fn) {
      s16x8 t;
#pragma unroll
      for (int j = 0; j < 8; ++j)
        ((short*)&t)[j] = *(const short*)(vp + (kc * 32 + hi * 8 + j) * 32 + fn * 16 + li);
      vf[kc][fn] = t;
    }

  __syncthreads();

  const f32x4 zf = (f32x4){0.f, 0.f, 0.f, 0.f};
  f32x4 o[4][2];
#pragma unroll
  for (int i = 0; i < 4; ++i) { o[i][0] = zf; o[i][1] = zf; }
#pragma unroll
  for (int i = 0; i < 4; ++i) {
    const int row = i * 16 + li;
#pragma unroll
    for (int kc = 0; kc < 2; ++kc) {
      const s16x8 pf = *(const s16x8*)((const char*)P + row * 128 + ((kc * 64 + hi * 16) ^ ((row & 7) << 4)));
      o[i][0] = MFMA16(pf, vf[kc][0], o[i][0]);
      o[i][1] = MFMA16(pf, vf[kc][1], o[i][1]);
    }
  }

  // O -> LDS (swizzled) -> coalesced stores (49 rows x 64B = 3136B)
#pragma unroll
  for (int i = 0; i < 4; ++i)
#pragma unroll
    for (int r = 0; r < 4; ++r) {
      const int q = i * 16 + hi * 4 + r;
      const float ri = rinv[i][r];
#pragma unroll
      for (int fn = 0; fn < 2; ++fn)
        *(unsigned short*)((char*)Olds + q * 64 + ((((fn * 16 + li) * 2)) ^ (((q >> 2) & 3) << 4))) =
            f2bf(o[i][fn][r] * ri);
    }
  __syncthreads();

  char* ob = (char*)(AOUT + rowbase);
#pragma unroll
  for (int c = 0; c < 3; ++c) {
    const int ofs = c * 1024 + lane * 16;
    const int rowL = ofs >> 6, col = ofs & 63;
    const s16x8 v = *(const s16x8*)((const char*)Olds + rowL * 64 + (col ^ (((rowL >> 2) & 3) << 4)));
    *(s16x8*)(ob + ofs) = v;
  }
  if (lane < 4) {
    const int ofs = 3072 + lane * 16;
    const int rowL = ofs >> 6, col = ofs & 63;
    const s16x8 v = *(const s16x8*)((const char*)Olds + rowL * 64 + (col ^ (((rowL >> 2) & 3) << 4)));
    *(s16x8*)(ob + ofs) = v;
  }
}

// ---------------------------------------------------------------------------
// GEMM3: 64x128 tile; A via global_load_lds (roll(+3) gather, inverse-swizzled
// source); B-frags direct from L2-hot W3; fp32 direct stores.
// ---------------------------------------------------------------------------
__global__ __launch_bounds__(256, 4)
void k_gemm_out(const unsigned short* __restrict__ A, const unsigned short* __restrict__ W3,
                const float* __restrict__ B, float* __restrict__ OUT) {
  __shared__ unsigned short Alds[64 * 128];   // 16KB
  const int tid = threadIdx.x;
  const int bm = blockIdx.x;                  // 0..1567
  const int lane = tid & 63, wid = tid >> 6;

#pragma unroll
  for (int c = 0; c < 4; ++c) {
    const int ofs = (wid << 12) + (c << 10) + (lane << 4);   // linear LDS dest byte
    const int rr = ofs >> 8;
    const int colb = ofs & 255;
    const int scol = colb ^ ((rr & 7) << 4);                 // inverse swizzle on source
    const int row = bm * 64 + rr;
    const int n = row / 3136;
    const int p = row - n * 3136;
    const int rf = p / 56, cf = p - rf * 56;
    int rs = rf + 53; if (rs >= 56) rs -= 56;                // roll(+3)
    int cs = cf + 53; if (cs >= 56) cs -= 56;
    const char* ga = (const char*)A + ((size_t)(n * 3136 + rs * 56 + cs)) * 256 + scol;
    gload_lds16(ga, (char*)Alds + (wid << 12) + (c << 10));
  }
  __syncthreads();

  const int li = lane & 15, hi = lane >> 4;
  const int rw = (wid >> 1) << 5, cw = (wid & 1) << 6;

  f32x4 acc[2][4];
#pragma unroll
  for (int i = 0; i < 2; ++i)
#pragma unroll
    for (int j = 0; j < 4; ++j) acc[i][j] = (f32x4){0.f, 0.f, 0.f, 0.f};

#pragma unroll
  for (int kc = 0; kc < 4; ++kc) {
    s16x8 af[2], bfr[4];
#pragma unroll
    for (int i = 0; i < 2; ++i) {
      const int ra = rw + i * 16 + li;
      af[i] = *(const s16x8*)((const char*)Alds + ra * 256 + ((kc * 64 + hi * 16) ^ ((ra & 7) << 4)));
    }
#pragma unroll
    for (int j = 0; j < 4; ++j)
      bfr[j] = *(const s16x8*)(W3 + (cw + j * 16 + li) * 128 + kc * 32 + hi * 8);
#pragma unroll
    for (int i = 0; i < 2; ++i)
#pragma unroll
      for (int j = 0; j < 4; ++j)
        acc[i][j] = MFMA16(af[i], bfr[j], acc[i][j]);
  }

  float bias4[4];
#pragma unroll
  for (int j = 0; j < 4; ++j) bias4[j] = B[cw + j * 16 + li];
#pragma unroll
  for (int i = 0; i < 2; ++i)
#pragma unroll
    for (int r = 0; r < 4; ++r) {
      const int row = bm * 64 + rw + i * 16 + hi * 4 + r;
      float* orow = OUT + (size_t)row * 128;
#pragma unroll
      for (int j = 0; j < 4; ++j)
        orow[cw + j * 16 + li] = acc[i][j][r] + bias4[j];
    }
}

extern "C" void kernel_launch(void* const* d_in, const int* in_sizes, int n_in,
                              void* d_out, int out_size, void* d_ws, size_t ws_size,
                              hipStream_t stream) {
  const float* x = (const float*)d_in[0];
  const float* qkv_w = (const float*)d_in[1];
  const float* qkv_b = (const float*)d_in[2];
  const float* out_w = (const float*)d_in[3];
  const float* out_b = (const float*)d_in[4];
  const float* rpe = (const float*)d_in[5];
  float* out = (float*)d_out;

  unsigned short* qkv_ws = (unsigned short*)d_ws;          // 3 planes
  unsigned short* aout = qkv_ws + 3 * PLANE;               // 1 plane
  unsigned short* W2 = aout + PLANE;                       // 3*16384 bf16
  unsigned short* W3 = W2 + 3 * 16384;                     // 16384 bf16
  float* BIASA = (float*)(W3 + 16384);                     // 4*4096 f32

  k_prep<<<36, 256, 0, stream>>>(qkv_w, out_w, rpe, W2, W3, BIASA);
  k_gemm_qkv<<<1568, 256, 0, stream>>>(x, W2, qkv_b, qkv_ws);
  k_attn<<<8192, 64, 0, stream>>>(qkv_ws, BIASA, aout);
  k_gemm_out<<<1568, 256, 0, stream>>>(aout, W3, out_b, out);
}

// Round 4
// 83.911 us; speedup vs baseline: 1.3529x; 1.3529x over previous
//
#include <hip/hip_runtime.h>
#include <hip/hip_bf16.h>

typedef __attribute__((ext_vector_type(4))) float f32x4;
typedef __attribute__((ext_vector_type(8))) short s16x8;

#define MFMA16(a, b, c) __builtin_amdgcn_mfma_f32_16x16x32_bf16(a, b, c, 0, 0, 0)

// elements per Q/K/V plane: 32 n * 12544 u * 32 d  (== row-major [100352][128])
#define PLANE ((size_t)12845056)
#define QSCALE 0.17677669529663687f

__device__ __forceinline__ unsigned short f2bf(float f) {
  union { float f; unsigned u; } v; v.f = f;
  unsigned u = v.u;
  u += 0x7fff + ((u >> 16) & 1);   // RNE
  return (unsigned short)(u >> 16);
}
__device__ __forceinline__ float bf2f(unsigned short h) {
  union { unsigned u; float f; } v; v.u = ((unsigned)h) << 16;
  return v.f;
}

typedef const __attribute__((address_space(1))) char gas_char;
typedef __attribute__((address_space(3))) char las_char;
__device__ __forceinline__ void gload_lds16(const void* g, void* l) {
  __builtin_amdgcn_global_load_lds((gas_char*)g, (las_char*)l, 16, 0, 0);
}

// ---------------------------------------------------------------------------
// Prepass: W2[s][c2][k] bf16 PRE-SWIZZLED rows (Q-part pre-scaled), W3 same,
// BIASA[cl][ij][lane][4] = bias+masks in MFMA C-operand layout.
// ---------------------------------------------------------------------------
__global__ void k_prep(const float* __restrict__ QW, const float* __restrict__ OW,
                       const float* __restrict__ RPE,
                       unsigned short* __restrict__ W2, unsigned short* __restrict__ W3,
                       float* __restrict__ BIASA) {
  const int b = blockIdx.x, t = threadIdx.x;
  if (b < 24) {                       // qkv_w: 3*128*128, swizzled [s][c2][k]
    const int e = (b * 256 + t) * 8;
    const int s = e >> 14;
    const int c2 = (e & 16383) >> 7;
    const int k0 = e & 127;
    const float sf = (s == 0) ? QSCALE : 1.0f;
    const float* src = QW + (size_t)(c2 * 3 + s) * 128 + k0;
    s16x8 h;
#pragma unroll
    for (int q = 0; q < 8; ++q) ((short*)&h)[q] = (short)f2bf(src[q] * sf);
    *(s16x8*)((char*)(W2 + (size_t)s * 16384 + c2 * 128) + ((k0 * 2) ^ ((c2 & 7) << 4))) = h;
  } else if (b < 32) {                // out_w: 128*128 swizzled
    const int e = ((b - 24) * 256 + t) * 8;
    const int c = e >> 7;
    const int k0 = e & 127;
    const float* src = OW + (size_t)c * 128 + k0;
    s16x8 h;
#pragma unroll
    for (int q = 0; q < 8; ++q) ((short*)&h)[q] = (short)f2bf(src[q]);
    *(s16x8*)((char*)(W3 + c * 128) + ((k0 * 2) ^ ((c & 7) << 4))) = h;
  } else {                            // bias tables in acc-fragment layout
    const int cl = b - 32;
    const int rm = cl >> 1, cm = cl & 1;
    for (int w = 0; w < 16; ++w) {
      const int idx = w * 256 + t;       // ((i*4+j)*64 + lane)*4 + rr
      const int rr = idx & 3;
      const int lane = (idx >> 2) & 63;
      const int ij = idx >> 8;
      const int q = (ij >> 2) * 16 + (lane >> 4) * 4 + rr;
      const int k = (ij & 3) * 16 + (lane & 15);
      float v;
      if (q >= 49 || k >= 49) v = -1.0e30f;
      else {
        const int xq = q / 7, yq = q - xq * 7;
        const int xk = k / 7, yk = k - xk * 7;
        v = RPE[(xk - xq + 6) * 13 + (yk - yq + 6)];
        if (rm && ((xq >= 4) != (xk >= 4))) v = -1.0e30f;
        if (cm && (((yq == 4) && (yk < 4)) || ((yq < 4) && (yk >= 4)))) v = -1.0e30f;
      }
      BIASA[cl * 4096 + idx] = v;
    }
  }
}

// ---------------------------------------------------------------------------
// GEMM1: 64x128 tile. A-fragments DIRECT global->VGPR (coalesced 128B/row
// chunks, in-register cvt). B staged in 32KB LDS via global_load_lds from
// pre-swizzled W2, single-buffered across the 3 s-passes.
// ---------------------------------------------------------------------------
__global__ __launch_bounds__(256, 4)
void k_gemm_qkv(const float* __restrict__ X, const unsigned short* __restrict__ W2,
                const float* __restrict__ B, unsigned short* __restrict__ OUT) {
  __shared__ unsigned short Blds[16384];   // 32KB
  const int tid = threadIdx.x;
  const int bm = blockIdx.x;               // 0..1567
  const int lane = tid & 63, wid = tid >> 6;

  // issue B(s=0) async
  {
    const char* gb = (const char*)W2 + (wid << 13) + (lane << 4);
    char* lb = (char*)Blds + (wid << 13) + (lane << 4);
#pragma unroll
    for (int r = 0; r < 8; ++r) gload_lds16(gb + (r << 10), lb + (r << 10));
  }

  const int li = lane & 15, hi = lane >> 4;
  const int rw = (wid >> 1) << 5;   // 0 or 32
  const int cw = (wid & 1) << 6;    // 0 or 64

  // A-fragments direct from global, converted in-register
  s16x8 af[4][2];   // [kc][i]
#pragma unroll
  for (int i = 0; i < 2; ++i) {
    const int row = bm * 64 + rw + i * 16 + li;
    const int n = row / 3136;
    const int p = row - n * 3136;
    const int r_ = p / 56, c_ = p - r_ * 56;
    int ro = r_ + 4; if (ro >= 56) ro -= 56;   // roll(-4)
    int co = c_ + 4; if (co >= 56) co -= 56;
    const float* src = X + (((size_t)n * 3136 + ro * 56 + co) << 7) + hi * 8;
#pragma unroll
    for (int kc = 0; kc < 4; ++kc) {
      const f32x4 v0 = *(const f32x4*)(src + kc * 32);
      const f32x4 v1 = *(const f32x4*)(src + kc * 32 + 4);
      s16x8 h;
      h[0] = (short)f2bf(v0.x); h[1] = (short)f2bf(v0.y);
      h[2] = (short)f2bf(v0.z); h[3] = (short)f2bf(v0.w);
      h[4] = (short)f2bf(v1.x); h[5] = (short)f2bf(v1.y);
      h[6] = (short)f2bf(v1.z); h[7] = (short)f2bf(v1.w);
      af[kc][i] = h;
    }
  }
  __syncthreads();   // B(0) landed

  for (int s = 0; s < 3; ++s) {
    f32x4 acc[2][4];
#pragma unroll
    for (int i = 0; i < 2; ++i)
#pragma unroll
      for (int j = 0; j < 4; ++j) acc[i][j] = (f32x4){0.f, 0.f, 0.f, 0.f};

#pragma unroll
    for (int kc = 0; kc < 4; ++kc) {
      s16x8 bfr[4];
#pragma unroll
      for (int j = 0; j < 4; ++j) {
        const int cb = cw + j * 16 + li;
        bfr[j] = *(const s16x8*)((const char*)Blds + cb * 256 + ((kc * 64 + hi * 16) ^ ((cb & 7) << 4)));
      }
#pragma unroll
      for (int i = 0; i < 2; ++i)
#pragma unroll
        for (int j = 0; j < 4; ++j)
          acc[i][j] = MFMA16(af[kc][i], bfr[j], acc[i][j]);
    }

    __syncthreads();                 // all waves done reading Blds(s)
    if (s < 2) {                     // prefetch B(s+1) under the epilogue
      const char* gb = (const char*)W2 + (size_t)(s + 1) * 32768 + (wid << 13) + (lane << 4);
      char* lb = (char*)Blds + (wid << 13) + (lane << 4);
#pragma unroll
      for (int r = 0; r < 8; ++r) gload_lds16(gb + (r << 10), lb + (r << 10));
    }

    const float bsf = (s == 0) ? QSCALE : 1.0f;
    float bias4[4];
#pragma unroll
    for (int j = 0; j < 4; ++j) bias4[j] = B[(cw + j * 16 + li) * 3 + s] * bsf;

    unsigned short* outS = OUT + (size_t)s * PLANE;
#pragma unroll
    for (int i = 0; i < 2; ++i)
#pragma unroll
      for (int r = 0; r < 4; ++r) {
        const size_t rb = (size_t)(bm * 64 + rw + i * 16 + hi * 4 + r) * 128;
#pragma unroll
        for (int j = 0; j < 4; ++j)
          outS[rb + cw + j * 16 + li] = f2bf(acc[i][j][r] + bias4[j]);
      }

    if (s < 2) __syncthreads();      // B(s+1) landed
  }
}

// ---------------------------------------------------------------------------
// Attention: 4 windows per 256-thread block (1 wave each). Bias via MFMA C-in.
// P through per-wave swizzled LDS; V-frags + O-stores direct global.
// ---------------------------------------------------------------------------
__global__ __launch_bounds__(256, 5)
void k_attn(const unsigned short* __restrict__ QKV, const float* __restrict__ BIASA,
            unsigned short* __restrict__ AOUT) {
  __shared__ unsigned short P[4 * 64 * 64];    // 8KB per wave

  const int tid = threadIdx.x;
  const int lane = tid & 63, wid = tid >> 6;
  const int w = blockIdx.x * 4 + wid;     // window 0..8191
  const int n = w >> 8;
  const int rem = w & 255;
  const int wh = (rem >> 3) & 7;
  const int ww = rem & 7;
  const size_t rowbase = ((size_t)(n * 12544 + rem * 49)) << 5;
  const unsigned short* qp = QKV + rowbase;
  const unsigned short* kp = qp + PLANE;
  const unsigned short* vp = kp + PLANE;
  const int cl = (wh == 7 ? 2 : 0) + (ww == 7 ? 1 : 0);
  const f32x4* bptr = (const f32x4*)(BIASA + (size_t)cl * 4096) + lane;
  char* Pw = (char*)P + wid * 8192;

  const int li = lane & 15, hi = lane >> 4;

  s16x8 qf[4], kf[4];
#pragma unroll
  for (int i = 0; i < 4; ++i) {
    qf[i] = *(const s16x8*)(qp + (i * 16 + li) * 32 + hi * 8);
    kf[i] = *(const s16x8*)(kp + (i * 16 + li) * 32 + hi * 8);
  }

  f32x4 sc[4][4];
#pragma unroll
  for (int i = 0; i < 4; ++i)
#pragma unroll
    for (int j = 0; j < 4; ++j) sc[i][j] = bptr[(i * 4 + j) * 64];
#pragma unroll
  for (int i = 0; i < 4; ++i)
#pragma unroll
    for (int j = 0; j < 4; ++j)
      sc[i][j] = MFMA16(qf[i], kf[j], sc[i][j]);   // logits incl. bias+mask

  float rinv[4][4];
#pragma unroll
  for (int i = 0; i < 4; ++i) {
#pragma unroll
    for (int r = 0; r < 4; ++r) {
      const int q = i * 16 + hi * 4 + r;
      float sum = 0.f;
      unsigned short pb[4];
#pragma unroll
      for (int j = 0; j < 4; ++j) {
        const unsigned short b = f2bf(__expf(sc[i][j][r]));
        pb[j] = b;
        sum += bf2f(b);
      }
#pragma unroll
      for (int d = 1; d < 16; d <<= 1) sum += __shfl_xor(sum, d);
      rinv[i][r] = 1.0f / sum;
#pragma unroll
      for (int j = 0; j < 4; ++j)
        *(unsigned short*)(Pw + q * 128 + (((j * 16 + li) * 2) ^ ((q & 7) << 4))) = pb[j];
    }
  }

  // V B-fragments direct from global (L2-hot)
  s16x8 vf[2][2];
#pragma unroll
  for (int kc = 0; kc < 2; ++kc)
#pragma unroll
    for (int fn = 0; fn < 2; ++fn) {
      s16x8 t;
#pragma unroll
      for (int j = 0; j < 8; ++j)
        ((short*)&t)[j] = *(const short*)(vp + (kc * 32 + hi * 8 + j) * 32 + fn * 16 + li);
      vf[kc][fn] = t;
    }

  __syncthreads();

  const f32x4 zf = (f32x4){0.f, 0.f, 0.f, 0.f};
  f32x4 o[4][2];
#pragma unroll
  for (int i = 0; i < 4; ++i) { o[i][0] = zf; o[i][1] = zf; }
#pragma unroll
  for (int i = 0; i < 4; ++i) {
    const int row = i * 16 + li;
#pragma unroll
    for (int kc = 0; kc < 2; ++kc) {
      const s16x8 pf = *(const s16x8*)(Pw + row * 128 + ((kc * 64 + hi * 16) ^ ((row & 7) << 4)));
      o[i][0] = MFMA16(pf, vf[kc][0], o[i][0]);
      o[i][1] = MFMA16(pf, vf[kc][1], o[i][1]);
    }
  }

  unsigned short* obase = AOUT + rowbase;
#pragma unroll
  for (int i = 0; i < 4; ++i)
#pragma unroll
    for (int r = 0; r < 4; ++r) {
      const int q = i * 16 + hi * 4 + r;
      if (q < 49) {
        const float ri = rinv[i][r];
        obase[q * 32 + li] = f2bf(o[i][0][r] * ri);
        obase[q * 32 + 16 + li] = f2bf(o[i][1][r] * ri);
      }
    }
}

// ---------------------------------------------------------------------------
// GEMM3: 64x128 tile; A and B both via global_load_lds (A: roll(+3) gather
// with inverse-swizzled source; B: pre-swizzled W3). fp32 direct stores.
// ---------------------------------------------------------------------------
__global__ __launch_bounds__(256, 3)
void k_gemm_out(const unsigned short* __restrict__ A, const unsigned short* __restrict__ W3,
                const float* __restrict__ B, float* __restrict__ OUT) {
  __shared__ unsigned short Alds[64 * 128];   // 16KB
  __shared__ unsigned short Blds[16384];      // 32KB
  const int tid = threadIdx.x;
  const int bm = blockIdx.x;                  // 0..1567
  const int lane = tid & 63, wid = tid >> 6;

  {
    const char* gb = (const char*)W3 + (wid << 13) + (lane << 4);
    char* lb = (char*)Blds + (wid << 13) + (lane << 4);
#pragma unroll
    for (int r = 0; r < 8; ++r) gload_lds16(gb + (r << 10), lb + (r << 10));
  }
#pragma unroll
  for (int c = 0; c < 4; ++c) {
    const int ofs = (wid << 12) + (c << 10) + (lane << 4);   // linear LDS dest byte
    const int rr = ofs >> 8;
    const int colb = ofs & 255;
    const int scol = colb ^ ((rr & 7) << 4);                 // inverse swizzle on source
    const int row = bm * 64 + rr;
    const int n = row / 3136;
    const int p = row - n * 3136;
    const int rf = p / 56, cf = p - rf * 56;
    int rs = rf + 53; if (rs >= 56) rs -= 56;                // roll(+3)
    int cs = cf + 53; if (cs >= 56) cs -= 56;
    const char* ga = (const char*)A + ((size_t)(n * 3136 + rs * 56 + cs)) * 256 + scol;
    gload_lds16(ga, (char*)Alds + ofs);
  }
  __syncthreads();

  const int li = lane & 15, hi = lane >> 4;
  const int rw = (wid >> 1) << 5, cw = (wid & 1) << 6;

  f32x4 acc[2][4];
#pragma unroll
  for (int i = 0; i < 2; ++i)
#pragma unroll
    for (int j = 0; j < 4; ++j) acc[i][j] = (f32x4){0.f, 0.f, 0.f, 0.f};

#pragma unroll
  for (int kc = 0; kc < 4; ++kc) {
    s16x8 af[2], bfr[4];
#pragma unroll
    for (int i = 0; i < 2; ++i) {
      const int ra = rw + i * 16 + li;
      af[i] = *(const s16x8*)((const char*)Alds + ra * 256 + ((kc * 64 + hi * 16) ^ ((ra & 7) << 4)));
    }
#pragma unroll
    for (int j = 0; j < 4; ++j) {
      const int cb = cw + j * 16 + li;
      bfr[j] = *(const s16x8*)((const char*)Blds + cb * 256 + ((kc * 64 + hi * 16) ^ ((cb & 7) << 4)));
    }
#pragma unroll
    for (int i = 0; i < 2; ++i)
#pragma unroll
      for (int j = 0; j < 4; ++j)
        acc[i][j] = MFMA16(af[i], bfr[j], acc[i][j]);
  }

  float bias4[4];
#pragma unroll
  for (int j = 0; j < 4; ++j) bias4[j] = B[cw + j * 16 + li];
#pragma unroll
  for (int i = 0; i < 2; ++i)
#pragma unroll
    for (int r = 0; r < 4; ++r) {
      const int row = bm * 64 + rw + i * 16 + hi * 4 + r;
      float* orow = OUT + (size_t)row * 128;
#pragma unroll
      for (int j = 0; j < 4; ++j)
        orow[cw + j * 16 + li] = acc[i][j][r] + bias4[j];
    }
}

extern "C" void kernel_launch(void* const* d_in, const int* in_sizes, int n_in,
                              void* d_out, int out_size, void* d_ws, size_t ws_size,
                              hipStream_t stream) {
  const float* x = (const float*)d_in[0];
  const float* qkv_w = (const float*)d_in[1];
  const float* qkv_b = (const float*)d_in[2];
  const float* out_w = (const float*)d_in[3];
  const float* out_b = (const float*)d_in[4];
  const float* rpe = (const float*)d_in[5];
  float* out = (float*)d_out;

  unsigned short* qkv_ws = (unsigned short*)d_ws;          // 3 planes
  unsigned short* aout = qkv_ws + 3 * PLANE;               // 1 plane
  unsigned short* W2 = aout + PLANE;                       // 3*16384 bf16
  unsigned short* W3 = W2 + 3 * 16384;                     // 16384 bf16
  float* BIASA = (float*)(W3 + 16384);                     // 4*4096 f32

  k_prep<<<36, 256, 0, stream>>>(qkv_w, out_w, rpe, W2, W3, BIASA);
  k_gemm_qkv<<<1568, 256, 0, stream>>>(x, W2, qkv_b, qkv_ws);
  k_attn<<<2048, 256, 0, stream>>>(qkv_ws, BIASA, aout);
  k_gemm_out<<<1568, 256, 0, stream>>>(aout, W3, out_b, out);
}

// Round 5
// 83.030 us; speedup vs baseline: 1.3672x; 1.0106x over previous
//
#include <hip/hip_runtime.h>
#include <hip/hip_bf16.h>

typedef __attribute__((ext_vector_type(4))) float f32x4;
typedef __attribute__((ext_vector_type(8))) short s16x8;

#define MFMA16(a, b, c) __builtin_amdgcn_mfma_f32_16x16x32_bf16(a, b, c, 0, 0, 0)

// elements per Q/K/V plane: 32 n * 12544 u * 32 d  (== row-major [100352][128])
#define PLANE ((size_t)12845056)
#define QSCALE 0.17677669529663687f

__device__ __forceinline__ unsigned short f2bf(float f) {
  union { float f; unsigned u; } v; v.f = f;
  unsigned u = v.u;
  u += 0x7fff + ((u >> 16) & 1);   // RNE
  return (unsigned short)(u >> 16);
}
__device__ __forceinline__ float bf2f(unsigned short h) {
  union { unsigned u; float f; } v; v.u = ((unsigned)h) << 16;
  return v.f;
}

typedef const __attribute__((address_space(1))) char gas_char;
typedef __attribute__((address_space(3))) char las_char;
__device__ __forceinline__ void gload_lds16(const void* g, void* l) {
  __builtin_amdgcn_global_load_lds((gas_char*)g, (las_char*)l, 16, 0, 0);
}

// ---------------------------------------------------------------------------
// Prepass: W2[s][c2][k] bf16 PRE-SWIZZLED rows (Q-part pre-scaled), W3 same,
// BIASA[cl][ij][lane][4] = bias+masks in MFMA C-operand layout.
// ---------------------------------------------------------------------------
__global__ void k_prep(const float* __restrict__ QW, const float* __restrict__ OW,
                       const float* __restrict__ RPE,
                       unsigned short* __restrict__ W2, unsigned short* __restrict__ W3,
                       float* __restrict__ BIASA) {
  const int b = blockIdx.x, t = threadIdx.x;
  if (b < 24) {                       // qkv_w: 3*128*128, swizzled [s][c2][k]
    const int e = (b * 256 + t) * 8;
    const int s = e >> 14;
    const int c2 = (e & 16383) >> 7;
    const int k0 = e & 127;
    const float sf = (s == 0) ? QSCALE : 1.0f;
    const float* src = QW + (size_t)(c2 * 3 + s) * 128 + k0;
    s16x8 h;
#pragma unroll
    for (int q = 0; q < 8; ++q) ((short*)&h)[q] = (short)f2bf(src[q] * sf);
    *(s16x8*)((char*)(W2 + (size_t)s * 16384 + c2 * 128) + ((k0 * 2) ^ ((c2 & 7) << 4))) = h;
  } else if (b < 32) {                // out_w: 128*128 swizzled
    const int e = ((b - 24) * 256 + t) * 8;
    const int c = e >> 7;
    const int k0 = e & 127;
    const float* src = OW + (size_t)c * 128 + k0;
    s16x8 h;
#pragma unroll
    for (int q = 0; q < 8; ++q) ((short*)&h)[q] = (short)f2bf(src[q]);
    *(s16x8*)((char*)(W3 + c * 128) + ((k0 * 2) ^ ((c & 7) << 4))) = h;
  } else {                            // bias tables in acc-fragment layout
    const int cl = b - 32;
    const int rm = cl >> 1, cm = cl & 1;
    for (int w = 0; w < 16; ++w) {
      const int idx = w * 256 + t;       // ((i*4+j)*64 + lane)*4 + rr
      const int rr = idx & 3;
      const int lane = (idx >> 2) & 63;
      const int ij = idx >> 8;
      const int q = (ij >> 2) * 16 + (lane >> 4) * 4 + rr;
      const int k = (ij & 3) * 16 + (lane & 15);
      float v;
      if (q >= 49 || k >= 49) v = -1.0e30f;
      else {
        const int xq = q / 7, yq = q - xq * 7;
        const int xk = k / 7, yk = k - xk * 7;
        v = RPE[(xk - xq + 6) * 13 + (yk - yq + 6)];
        if (rm && ((xq >= 4) != (xk >= 4))) v = -1.0e30f;
        if (cm && (((yq == 4) && (yk < 4)) || ((yq < 4) && (yk >= 4)))) v = -1.0e30f;
      }
      BIASA[cl * 4096 + idx] = v;
    }
  }
}

// ---------------------------------------------------------------------------
// GEMM1: 64x128 tile. A direct global->VGPR. B double-buffered in LDS.
// ALL C deferred in packed bf16 VGPRs; single end-stage through LDS ->
// 12 coalesced 16B stores. NO mid-kernel global-store drains.
// ---------------------------------------------------------------------------
__global__ __launch_bounds__(256, 2)
void k_gemm_qkv(const float* __restrict__ X, const unsigned short* __restrict__ W2,
                const float* __restrict__ B, unsigned short* __restrict__ OUT) {
  __shared__ char LDS[65536];              // 2 x 32KB B buffers; reused for C (48KB)
  const int tid = threadIdx.x;
  const int bm = blockIdx.x;               // 0..1567
  const int lane = tid & 63, wid = tid >> 6;
  const int li = lane & 15, hi = lane >> 4;
  const int rw = (wid >> 1) << 5;   // 0 or 32
  const int cw = (wid & 1) << 6;    // 0 or 64

  // issue B(0) and B(1) async
#pragma unroll
  for (int s = 0; s < 2; ++s) {
    const char* gb = (const char*)W2 + s * 32768 + (wid << 13) + (lane << 4);
    char* lb = LDS + s * 32768 + (wid << 13) + (lane << 4);
#pragma unroll
    for (int r = 0; r < 8; ++r) gload_lds16(gb + (r << 10), lb + (r << 10));
  }

  // bias, all 3 planes, loaded once
  float bias[3][4];
#pragma unroll
  for (int s = 0; s < 3; ++s)
#pragma unroll
    for (int j = 0; j < 4; ++j)
      bias[s][j] = B[(cw + j * 16 + li) * 3 + s] * ((s == 0) ? QSCALE : 1.0f);

  // A-fragments direct from global, converted in-register
  s16x8 af[4][2];   // [kc][i]
#pragma unroll
  for (int i = 0; i < 2; ++i) {
    const int row = bm * 64 + rw + i * 16 + li;
    const int n = row / 3136;
    const int p = row - n * 3136;
    const int r_ = p / 56, c_ = p - r_ * 56;
    int ro = r_ + 4; if (ro >= 56) ro -= 56;   // roll(-4)
    int co = c_ + 4; if (co >= 56) co -= 56;
    const float* src = X + (((size_t)n * 3136 + ro * 56 + co) << 7) + hi * 8;
#pragma unroll
    for (int kc = 0; kc < 4; ++kc) {
      const f32x4 v0 = *(const f32x4*)(src + kc * 32);
      const f32x4 v1 = *(const f32x4*)(src + kc * 32 + 4);
      s16x8 h;
      h[0] = (short)f2bf(v0.x); h[1] = (short)f2bf(v0.y);
      h[2] = (short)f2bf(v0.z); h[3] = (short)f2bf(v0.w);
      h[4] = (short)f2bf(v1.x); h[5] = (short)f2bf(v1.y);
      h[6] = (short)f2bf(v1.z); h[7] = (short)f2bf(v1.w);
      af[kc][i] = h;
    }
  }

  s16x8 pc0[4], pc1[4], pc2[4];   // packed bf16 C, one pass each

#define GEMM_PASS(BUFOFF, S, PCV)                                               \
  {                                                                             \
    f32x4 acc[2][4];                                                            \
    _Pragma("unroll")                                                           \
    for (int i = 0; i < 2; ++i)                                                 \
      _Pragma("unroll")                                                         \
      for (int j = 0; j < 4; ++j) acc[i][j] = (f32x4){0.f, 0.f, 0.f, 0.f};      \
    _Pragma("unroll")                                                           \
    for (int kc = 0; kc < 4; ++kc) {                                            \
      s16x8 bfr[4];                                                             \
      _Pragma("unroll")                                                         \
      for (int j = 0; j < 4; ++j) {                                             \
        const int cb = cw + j * 16 + li;                                        \
        bfr[j] = *(const s16x8*)(LDS + (BUFOFF) + cb * 256 +                    \
                                 ((kc * 64 + hi * 16) ^ ((cb & 7) << 4)));      \
      }                                                                         \
      _Pragma("unroll")                                                         \
      for (int i = 0; i < 2; ++i)                                               \
        _Pragma("unroll")                                                       \
        for (int j = 0; j < 4; ++j)                                             \
          acc[i][j] = MFMA16(af[kc][i], bfr[j], acc[i][j]);                     \
    }                                                                           \
    _Pragma("unroll")                                                           \
    for (int v = 0; v < 4; ++v) {                                               \
      s16x8 h;                                                                  \
      _Pragma("unroll")                                                         \
      for (int e = 0; e < 8; ++e) {                                             \
        const int idx = v * 8 + e;                                              \
        const int i = idx >> 4, r = (idx >> 2) & 3, j = idx & 3;                \
        h[e] = (short)f2bf(acc[i][j][r] + bias[S][j]);                          \
      }                                                                         \
      PCV[v] = h;                                                               \
    }                                                                           \
  }

  __syncthreads();                  // B0,B1 landed (A-loads already consumed)
  GEMM_PASS(0, 0, pc0)
  __syncthreads();                  // all waves done reading buf0 (cheap: nothing in flight)
  {                                 // issue B(2) into buf0
    const char* gb = (const char*)W2 + 2 * 32768 + (wid << 13) + (lane << 4);
    char* lb = LDS + (wid << 13) + (lane << 4);
#pragma unroll
    for (int r = 0; r < 8; ++r) gload_lds16(gb + (r << 10), lb + (r << 10));
  }
  GEMM_PASS(32768, 1, pc1)
  __syncthreads();                  // B2 landed (covered by pass1 compute)
  GEMM_PASS(0, 2, pc2)
  __syncthreads();                  // all waves done reading buf0; lgkm-only

  // stage all C through LDS (48KB), then 12 coalesced 16B stores
#define C_STAGE(S, PCV)                                                         \
  _Pragma("unroll")                                                             \
  for (int v = 0; v < 4; ++v)                                                   \
    _Pragma("unroll")                                                           \
    for (int e = 0; e < 8; ++e) {                                               \
      const int idx = v * 8 + e;                                                \
      const int i = idx >> 4, r = (idx >> 2) & 3, j = idx & 3;                  \
      const int row = rw + i * 16 + hi * 4 + r;                                 \
      const int col = cw + j * 16 + li;                                         \
      *(unsigned short*)(LDS + (S)*16384 + row * 256 +                          \
                         ((col * 2) ^ ((row & 7) << 4))) = (unsigned short)PCV[v][e]; \
    }
  C_STAGE(0, pc0)
  C_STAGE(1, pc1)
  C_STAGE(2, pc2)
  __syncthreads();                  // lgkm-only drain

#pragma unroll
  for (int c = 0; c < 12; ++c) {
    const int ofs = c * 4096 + tid * 16;      // byte offset within 48KB
    const int s = ofs >> 14;
    const int po = ofs & 16383;
    const int row = po >> 8, colb = po & 255;
    const s16x8 v = *(const s16x8*)(LDS + s * 16384 + row * 256 + (colb ^ ((row & 7) << 4)));
    *(s16x8*)((char*)OUT + (size_t)s * (PLANE * 2) + (size_t)bm * 16384 + po) = v;
  }
#undef GEMM_PASS
#undef C_STAGE
}

// ---------------------------------------------------------------------------
// Attention: 4 windows per block, 1 wave each, NO block barrier (P-LDS is
// wave-private). Bias via MFMA C-in. V-frags + O-stores direct global.
// ---------------------------------------------------------------------------
__global__ __launch_bounds__(256, 5)
void k_attn(const unsigned short* __restrict__ QKV, const float* __restrict__ BIASA,
            unsigned short* __restrict__ AOUT) {
  __shared__ unsigned short P[4 * 64 * 64];    // 8KB per wave, wave-private

  const int tid = threadIdx.x;
  const int lane = tid & 63, wid = tid >> 6;
  const int w = blockIdx.x * 4 + wid;     // window 0..8191
  const int n = w >> 8;
  const int rem = w & 255;
  const int wh = (rem >> 3) & 7;
  const int ww = rem & 7;
  const size_t rowbase = ((size_t)(n * 12544 + rem * 49)) << 5;
  const unsigned short* qp = QKV + rowbase;
  const unsigned short* kp = qp + PLANE;
  const unsigned short* vp = kp + PLANE;
  const int cl = (wh == 7 ? 2 : 0) + (ww == 7 ? 1 : 0);
  const f32x4* bptr = (const f32x4*)(BIASA + (size_t)cl * 4096) + lane;
  char* Pw = (char*)P + wid * 8192;

  const int li = lane & 15, hi = lane >> 4;

  s16x8 qf[4], kf[4];
#pragma unroll
  for (int i = 0; i < 4; ++i) {
    qf[i] = *(const s16x8*)(qp + (i * 16 + li) * 32 + hi * 8);
    kf[i] = *(const s16x8*)(kp + (i * 16 + li) * 32 + hi * 8);
  }

  f32x4 sc[4][4];
#pragma unroll
  for (int i = 0; i < 4; ++i)
#pragma unroll
    for (int j = 0; j < 4; ++j) sc[i][j] = bptr[(i * 4 + j) * 64];
#pragma unroll
  for (int i = 0; i < 4; ++i)
#pragma unroll
    for (int j = 0; j < 4; ++j)
      sc[i][j] = MFMA16(qf[i], kf[j], sc[i][j]);   // logits incl. bias+mask

  float rinv[4][4];
#pragma unroll
  for (int i = 0; i < 4; ++i) {
#pragma unroll
    for (int r = 0; r < 4; ++r) {
      const int q = i * 16 + hi * 4 + r;
      float sum = 0.f;
      unsigned short pb[4];
#pragma unroll
      for (int j = 0; j < 4; ++j) {
        const unsigned short b = f2bf(__expf(sc[i][j][r]));
        pb[j] = b;
        sum += bf2f(b);
      }
#pragma unroll
      for (int d = 1; d < 16; d <<= 1) sum += __shfl_xor(sum, d);
      rinv[i][r] = 1.0f / sum;
#pragma unroll
      for (int j = 0; j < 4; ++j)
        *(unsigned short*)(Pw + q * 128 + (((j * 16 + li) * 2) ^ ((q & 7) << 4))) = pb[j];
    }
  }

  // V B-fragments direct from global (L2-hot)
  s16x8 vf[2][2];
#pragma unroll
  for (int kc = 0; kc < 2; ++kc)
#pragma unroll
    for (int fn = 0; fn < 2; ++fn) {
      s16x8 t;
#pragma unroll
      for (int j = 0; j < 8; ++j)
        ((short*)&t)[j] = *(const short*)(vp + (kc * 32 + hi * 8 + j) * 32 + fn * 16 + li);
      vf[kc][fn] = t;
    }

  // no __syncthreads: P region is wave-private; compiler inserts lgkm waits

  const f32x4 zf = (f32x4){0.f, 0.f, 0.f, 0.f};
  f32x4 o[4][2];
#pragma unroll
  for (int i = 0; i < 4; ++i) { o[i][0] = zf; o[i][1] = zf; }
#pragma unroll
  for (int i = 0; i < 4; ++i) {
    const int row = i * 16 + li;
#pragma unroll
    for (int kc = 0; kc < 2; ++kc) {
      const s16x8 pf = *(const s16x8*)(Pw + row * 128 + ((kc * 64 + hi * 16) ^ ((row & 7) << 4)));
      o[i][0] = MFMA16(pf, vf[kc][0], o[i][0]);
      o[i][1] = MFMA16(pf, vf[kc][1], o[i][1]);
    }
  }

  unsigned short* obase = AOUT + rowbase;
#pragma unroll
  for (int i = 0; i < 4; ++i)
#pragma unroll
    for (int r = 0; r < 4; ++r) {
      const int q = i * 16 + hi * 4 + r;
      if (q < 49) {
        const float ri = rinv[i][r];
        obase[q * 32 + li] = f2bf(o[i][0][r] * ri);
        obase[q * 32 + 16 + li] = f2bf(o[i][1][r] * ri);
      }
    }
}

// ---------------------------------------------------------------------------
// GEMM3: 64x128 tile; A and B both via global_load_lds (A: roll(+3) gather
// with inverse-swizzled source; B: pre-swizzled W3). fp32 direct stores.
// ---------------------------------------------------------------------------
__global__ __launch_bounds__(256, 3)
void k_gemm_out(const unsigned short* __restrict__ A, const unsigned short* __restrict__ W3,
                const float* __restrict__ B, float* __restrict__ OUT) {
  __shared__ unsigned short Alds[64 * 128];   // 16KB
  __shared__ unsigned short Blds[16384];      // 32KB
  const int tid = threadIdx.x;
  const int bm = blockIdx.x;                  // 0..1567
  const int lane = tid & 63, wid = tid >> 6;

  {
    const char* gb = (const char*)W3 + (wid << 13) + (lane << 4);
    char* lb = (char*)Blds + (wid << 13) + (lane << 4);
#pragma unroll
    for (int r = 0; r < 8; ++r) gload_lds16(gb + (r << 10), lb + (r << 10));
  }
#pragma unroll
  for (int c = 0; c < 4; ++c) {
    const int ofs = (wid << 12) + (c << 10) + (lane << 4);   // linear LDS dest byte
    const int rr = ofs >> 8;
    const int colb = ofs & 255;
    const int scol = colb ^ ((rr & 7) << 4);                 // inverse swizzle on source
    const int row = bm * 64 + rr;
    const int n = row / 3136;
    const int p = row - n * 3136;
    const int rf = p / 56, cf = p - rf * 56;
    int rs = rf + 53; if (rs >= 56) rs -= 56;                // roll(+3)
    int cs = cf + 53; if (cs >= 56) cs -= 56;
    const char* ga = (const char*)A + ((size_t)(n * 3136 + rs * 56 + cs)) * 256 + scol;
    gload_lds16(ga, (char*)Alds + ofs);
  }
  __syncthreads();

  const int li = lane & 15, hi = lane >> 4;
  const int rw = (wid >> 1) << 5, cw = (wid & 1) << 6;

  f32x4 acc[2][4];
#pragma unroll
  for (int i = 0; i < 2; ++i)
#pragma unroll
    for (int j = 0; j < 4; ++j) acc[i][j] = (f32x4){0.f, 0.f, 0.f, 0.f};

#pragma unroll
  for (int kc = 0; kc < 4; ++kc) {
    s16x8 af[2], bfr[4];
#pragma unroll
    for (int i = 0; i < 2; ++i) {
      const int ra = rw + i * 16 + li;
      af[i] = *(const s16x8*)((const char*)Alds + ra * 256 + ((kc * 64 + hi * 16) ^ ((ra & 7) << 4)));
    }
#pragma unroll
    for (int j = 0; j < 4; ++j) {
      const int cb = cw + j * 16 + li;
      bfr[j] = *(const s16x8*)((const char*)Blds + cb * 256 + ((kc * 64 + hi * 16) ^ ((cb & 7) << 4)));
    }
#pragma unroll
    for (int i = 0; i < 2; ++i)
#pragma unroll
      for (int j = 0; j < 4; ++j)
        acc[i][j] = MFMA16(af[i], bfr[j], acc[i][j]);
  }

  float bias4[4];
#pragma unroll
  for (int j = 0; j < 4; ++j) bias4[j] = B[cw + j * 16 + li];
#pragma unroll
  for (int i = 0; i < 2; ++i)
#pragma unroll
    for (int r = 0; r < 4; ++r) {
      const int row = bm * 64 + rw + i * 16 + hi * 4 + r;
      float* orow = OUT + (size_t)row * 128;
#pragma unroll
      for (int j = 0; j < 4; ++j)
        orow[cw + j * 16 + li] = acc[i][j][r] + bias4[j];
    }
}

extern "C" void kernel_launch(void* const* d_in, const int* in_sizes, int n_in,
                              void* d_out, int out_size, void* d_ws, size_t ws_size,
                              hipStream_t stream) {
  const float* x = (const float*)d_in[0];
  const float* qkv_w = (const float*)d_in[1];
  const float* qkv_b = (const float*)d_in[2];
  const float* out_w = (const float*)d_in[3];
  const float* out_b = (const float*)d_in[4];
  const float* rpe = (const float*)d_in[5];
  float* out = (float*)d_out;

  unsigned short* qkv_ws = (unsigned short*)d_ws;          // 3 planes
  unsigned short* aout = qkv_ws + 3 * PLANE;               // 1 plane
  unsigned short* W2 = aout + PLANE;                       // 3*16384 bf16
  unsigned short* W3 = W2 + 3 * 16384;                     // 16384 bf16
  float* BIASA = (float*)(W3 + 16384);                     // 4*4096 f32

  k_prep<<<36, 256, 0, stream>>>(qkv_w, out_w, rpe, W2, W3, BIASA);
  k_gemm_qkv<<<1568, 256, 0, stream>>>(x, W2, qkv_b, qkv_ws);
  k_attn<<<2048, 256, 0, stream>>>(qkv_ws, BIASA, aout);
  k_gemm_out<<<1568, 256, 0, stream>>>(aout, W3, out_b, out);
}

// Round 6
// 77.598 us; speedup vs baseline: 1.4629x; 1.0700x over previous
//
#include <hip/hip_runtime.h>
#include <hip/hip_bf16.h>

typedef __attribute__((ext_vector_type(4))) float f32x4;
typedef __attribute__((ext_vector_type(8))) short s16x8;

#define MFMA16(a, b, c) __builtin_amdgcn_mfma_f32_16x16x32_bf16(a, b, c, 0, 0, 0)

#define PLANE ((size_t)12845056)
#define QSCALE 0.17677669529663687f

__device__ __forceinline__ unsigned short f2bf(float f) {
  union { float f; unsigned u; } v; v.f = f;
  unsigned u = v.u;
  u += 0x7fff + ((u >> 16) & 1);   // RNE
  return (unsigned short)(u >> 16);
}
__device__ __forceinline__ float bf2f(unsigned short h) {
  union { unsigned u; float f; } v; v.u = ((unsigned)h) << 16;
  return v.f;
}

typedef const __attribute__((address_space(1))) char gas_char;
typedef __attribute__((address_space(3))) char las_char;
__device__ __forceinline__ void gload_lds16(const void* g, void* l) {
  __builtin_amdgcn_global_load_lds((gas_char*)g, (las_char*)l, 16, 0, 0);
}

// ---------------------------------------------------------------------------
// Prepass: W2[s][c2][k] bf16 PRE-SWIZZLED rows (Q-part pre-scaled), W3 same,
// BIASA[cl][ij][lane][4] = bias+masks in MFMA C-operand layout.
// ---------------------------------------------------------------------------
__global__ void k_prep(const float* __restrict__ QW, const float* __restrict__ OW,
                       const float* __restrict__ RPE,
                       unsigned short* __restrict__ W2, unsigned short* __restrict__ W3,
                       float* __restrict__ BIASA) {
  const int b = blockIdx.x, t = threadIdx.x;
  if (b < 24) {                       // qkv_w: 3*128*128, swizzled [s][c2][k]
    const int e = (b * 256 + t) * 8;
    const int s = e >> 14;
    const int c2 = (e & 16383) >> 7;
    const int k0 = e & 127;
    const float sf = (s == 0) ? QSCALE : 1.0f;
    const float* src = QW + (size_t)(c2 * 3 + s) * 128 + k0;
    s16x8 h;
#pragma unroll
    for (int q = 0; q < 8; ++q) ((short*)&h)[q] = (short)f2bf(src[q] * sf);
    *(s16x8*)((char*)(W2 + (size_t)s * 16384 + c2 * 128) + ((k0 * 2) ^ ((c2 & 7) << 4))) = h;
  } else if (b < 32) {                // out_w: 128*128 swizzled
    const int e = ((b - 24) * 256 + t) * 8;
    const int c = e >> 7;
    const int k0 = e & 127;
    const float* src = OW + (size_t)c * 128 + k0;
    s16x8 h;
#pragma unroll
    for (int q = 0; q < 8; ++q) ((short*)&h)[q] = (short)f2bf(src[q]);
    *(s16x8*)((char*)(W3 + c * 128) + ((k0 * 2) ^ ((c & 7) << 4))) = h;
  } else {                            // bias tables in acc-fragment layout
    const int cl = b - 32;
    const int rm = cl >> 1, cm = cl & 1;
    for (int w = 0; w < 16; ++w) {
      const int idx = w * 256 + t;       // ((i*4+j)*64 + lane)*4 + rr
      const int rr = idx & 3;
      const int lane = (idx >> 2) & 63;
      const int ij = idx >> 8;
      const int q = (ij >> 2) * 16 + (lane >> 4) * 4 + rr;
      const int k = (ij & 3) * 16 + (lane & 15);
      float v;
      if (q >= 49 || k >= 49) v = -1.0e30f;
      else {
        const int xq = q / 7, yq = q - xq * 7;
        const int xk = k / 7, yk = k - xk * 7;
        v = RPE[(xk - xq + 6) * 13 + (yk - yq + 6)];
        if (rm && ((xq >= 4) != (xk >= 4))) v = -1.0e30f;
        if (cm && (((yq == 4) && (yk < 4)) || ((yq < 4) && (yk >= 4)))) v = -1.0e30f;
      }
      BIASA[cl * 4096 + idx] = v;
    }
  }
}

// ---------------------------------------------------------------------------
// FUSED gemm_qkv + attention.
// Block bm: n = bm/64, wb = bm%64; owns p-rows [49*wb, 49*wb+49) (tile padded
// to 64 rows) == windows g in [4*wb, 4*wb+4) exactly (no halo).
// 3 weight passes write Q/K/V tiles to LDS (C-row layout, XOR-swizzled);
// each wave then runs one window's attention from LDS; only the attention
// output (25 MB) goes to global.
// LDS: Q[16K] K[16K] V[16K] WB[32K, reused for P] = 80KB -> 2 blocks/CU.
// ---------------------------------------------------------------------------
#define Q_OFF 0
#define K_OFF 16384
#define V_OFF 32768
#define WB_OFF 49152

__global__ __launch_bounds__(256, 2)
void k_fused(const float* __restrict__ X, const unsigned short* __restrict__ W2,
             const float* __restrict__ B, const float* __restrict__ BIASA,
             unsigned short* __restrict__ AOUT) {
  __shared__ alignas(16) char LDS[81920];
  const int tid = threadIdx.x;
  const int bm = blockIdx.x;               // 0..2047
  const int n = bm >> 6;
  const int wb = bm & 63;
  const int p0 = wb * 49;
  const int lane = tid & 63, wid = tid >> 6;
  const int li = lane & 15, hi = lane >> 4;
  const int rw = (wid >> 1) << 5;   // 0 or 32
  const int cw = (wid & 1) << 6;    // 0 or 64

  // issue B(Q) async into WB
  {
    const char* gb = (const char*)W2 + (wid << 13) + (lane << 4);
    char* lb = LDS + WB_OFF + (wid << 13) + (lane << 4);
#pragma unroll
    for (int r = 0; r < 4; ++r) gload_lds16(gb + (r << 10), lb + (r << 10));
#pragma unroll
    for (int r = 4; r < 8; ++r) gload_lds16(gb + (r << 10), lb + (r << 10));
  }

  // bias for all 3 planes
  float bias[3][4];
#pragma unroll
  for (int s = 0; s < 3; ++s)
#pragma unroll
    for (int j = 0; j < 4; ++j)
      bias[s][j] = B[(cw + j * 16 + li) * 3 + s] * ((s == 0) ? QSCALE : 1.0f);

  // A-fragments direct from global, converted in-register
  s16x8 af[4][2];   // [kc][i]
#pragma unroll
  for (int i = 0; i < 2; ++i) {
    int p = p0 + rw + i * 16 + li;
    if (p > 3135) p = 3135;                    // pad rows (unused downstream)
    const int r_ = p / 56, c_ = p - r_ * 56;
    int ro = r_ + 4; if (ro >= 56) ro -= 56;   // roll(-4)
    int co = c_ + 4; if (co >= 56) co -= 56;
    const float* src = X + (((size_t)n * 3136 + ro * 56 + co) << 7) + hi * 8;
#pragma unroll
    for (int kc = 0; kc < 4; ++kc) {
      const f32x4 v0 = *(const f32x4*)(src + kc * 32);
      const f32x4 v1 = *(const f32x4*)(src + kc * 32 + 4);
      s16x8 h;
      h[0] = (short)f2bf(v0.x); h[1] = (short)f2bf(v0.y);
      h[2] = (short)f2bf(v0.z); h[3] = (short)f2bf(v0.w);
      h[4] = (short)f2bf(v1.x); h[5] = (short)f2bf(v1.y);
      h[6] = (short)f2bf(v1.z); h[7] = (short)f2bf(v1.w);
      af[kc][i] = h;
    }
  }
  __syncthreads();                  // B(Q) landed

#define FUSED_PASS(DST, S)                                                      \
  {                                                                             \
    f32x4 acc[2][4];                                                            \
    _Pragma("unroll")                                                           \
    for (int i = 0; i < 2; ++i)                                                 \
      _Pragma("unroll")                                                         \
      for (int j = 0; j < 4; ++j) acc[i][j] = (f32x4){0.f, 0.f, 0.f, 0.f};      \
    _Pragma("unroll")                                                           \
    for (int kc = 0; kc < 4; ++kc) {                                            \
      s16x8 bfr[4];                                                             \
      _Pragma("unroll")                                                         \
      for (int j = 0; j < 4; ++j) {                                             \
        const int cb = cw + j * 16 + li;                                        \
        bfr[j] = *(const s16x8*)(LDS + WB_OFF + cb * 256 +                      \
                                 ((kc * 64 + hi * 16) ^ ((cb & 7) << 4)));      \
      }                                                                         \
      _Pragma("unroll")                                                         \
      for (int i = 0; i < 2; ++i)                                               \
        _Pragma("unroll")                                                       \
        for (int j = 0; j < 4; ++j)                                             \
          acc[i][j] = MFMA16(af[kc][i], bfr[j], acc[i][j]);                     \
    }                                                                           \
    _Pragma("unroll")                                                           \
    for (int i = 0; i < 2; ++i)                                                 \
      _Pragma("unroll")                                                         \
      for (int r = 0; r < 4; ++r) {                                             \
        const int row = rw + i * 16 + hi * 4 + r;                               \
        _Pragma("unroll")                                                       \
        for (int j = 0; j < 4; ++j) {                                           \
          const int col = cw + j * 16 + li;                                     \
          *(unsigned short*)(LDS + (DST) + row * 256 +                          \
                             ((col * 2) ^ ((row & 7) << 4))) =                  \
              f2bf(acc[i][j][r] + bias[S][j]);                                  \
        }                                                                       \
      }                                                                         \
  }

  FUSED_PASS(Q_OFF, 0)
  __syncthreads();                  // everyone done reading WB(Q)
  {
    const char* gb = (const char*)W2 + 32768 + (wid << 13) + (lane << 4);
    char* lb = LDS + WB_OFF + (wid << 13) + (lane << 4);
#pragma unroll
    for (int r = 0; r < 8; ++r) gload_lds16(gb + (r << 10), lb + (r << 10));
  }
  __syncthreads();                  // B(K) landed
  FUSED_PASS(K_OFF, 1)
  __syncthreads();
  {
    const char* gb = (const char*)W2 + 65536 + (wid << 13) + (lane << 4);
    char* lb = LDS + WB_OFF + (wid << 13) + (lane << 4);
#pragma unroll
    for (int r = 0; r < 8; ++r) gload_lds16(gb + (r << 10), lb + (r << 10));
  }
  __syncthreads();                  // B(V) landed
  FUSED_PASS(V_OFF, 2)
  __syncthreads();                  // Q/K/V staged; WB region becomes P
#undef FUSED_PASS

  // ------------------------- attention (per wave) -------------------------
  const int g = wb * 4 + wid;              // window index within n, 0..255
  const int wh = (g >> 3) & 7;
  const int ww = g & 7;
  const int cl = (wh == 7 ? 2 : 0) + (ww == 7 ? 1 : 0);
  const f32x4* bptr = (const f32x4*)(BIASA + (size_t)cl * 4096) + lane;
  char* Pw = LDS + WB_OFF + wid * 8192;    // wave-private P
  const int uw = wid * 49;                 // wave's base u within block tile

  // Q/K fragments from LDS (C-row layout: row p=u>>2, col (u&3)*32 + d)
  s16x8 qf[4], kf[4];
#pragma unroll
  for (int i = 0; i < 4; ++i) {
    const int u = uw + i * 16 + li;
    const int p = u >> 2, cg = u & 3;
    const int byte = p * 256 + ((cg * 64 + hi * 16) ^ ((p & 7) << 4));
    qf[i] = *(const s16x8*)(LDS + Q_OFF + byte);
    kf[i] = *(const s16x8*)(LDS + K_OFF + byte);
  }

  f32x4 sc[4][4];
#pragma unroll
  for (int i = 0; i < 4; ++i)
#pragma unroll
    for (int j = 0; j < 4; ++j) sc[i][j] = bptr[(i * 4 + j) * 64];
#pragma unroll
  for (int i = 0; i < 4; ++i)
#pragma unroll
    for (int j = 0; j < 4; ++j)
      sc[i][j] = MFMA16(qf[i], kf[j], sc[i][j]);   // logits incl. bias+mask

  float rinv[4][4];
#pragma unroll
  for (int i = 0; i < 4; ++i) {
#pragma unroll
    for (int r = 0; r < 4; ++r) {
      const int q = i * 16 + hi * 4 + r;
      float sum = 0.f;
      unsigned short pb[4];
#pragma unroll
      for (int j = 0; j < 4; ++j) {
        const unsigned short b = f2bf(__expf(sc[i][j][r]));
        pb[j] = b;
        sum += bf2f(b);
      }
#pragma unroll
      for (int d = 1; d < 16; d <<= 1) sum += __shfl_xor(sum, d);
      rinv[i][r] = 1.0f / sum;
#pragma unroll
      for (int j = 0; j < 4; ++j)
        *(unsigned short*)(Pw + q * 128 + (((j * 16 + li) * 2) ^ ((q & 7) << 4))) = pb[j];
    }
  }

  // V^T fragments gathered from LDS V tile (t>=49 reads finite garbage, *0)
  s16x8 vf[2][2];
#pragma unroll
  for (int kc = 0; kc < 2; ++kc)
#pragma unroll
    for (int fn = 0; fn < 2; ++fn) {
      const int dd = fn * 16 + li;
      s16x8 tv;
#pragma unroll
      for (int jj = 0; jj < 8; ++jj) {
        const int u = uw + kc * 32 + hi * 8 + jj;
        const int p = u >> 2, cg = u & 3;
        tv[jj] = *(const short*)(LDS + V_OFF + p * 256 + ((cg * 64 + dd * 2) ^ ((p & 7) << 4)));
      }
      vf[kc][fn] = tv;
    }

  const f32x4 zf = (f32x4){0.f, 0.f, 0.f, 0.f};
  f32x4 o[4][2];
#pragma unroll
  for (int i = 0; i < 4; ++i) { o[i][0] = zf; o[i][1] = zf; }
#pragma unroll
  for (int i = 0; i < 4; ++i) {
    const int row = i * 16 + li;
#pragma unroll
    for (int kc = 0; kc < 2; ++kc) {
      const s16x8 pf = *(const s16x8*)(Pw + row * 128 + ((kc * 64 + hi * 16) ^ ((row & 7) << 4)));
      o[i][0] = MFMA16(pf, vf[kc][0], o[i][0]);
      o[i][1] = MFMA16(pf, vf[kc][1], o[i][1]);
    }
  }

  unsigned short* obase = AOUT + (((size_t)(n * 12544 + g * 49)) << 5);
#pragma unroll
  for (int i = 0; i < 4; ++i)
#pragma unroll
    for (int r = 0; r < 4; ++r) {
      const int q = i * 16 + hi * 4 + r;
      if (q < 49) {
        const float ri = rinv[i][r];
        obase[q * 32 + li] = f2bf(o[i][0][r] * ri);
        obase[q * 32 + 16 + li] = f2bf(o[i][1][r] * ri);
      }
    }
}

// ---------------------------------------------------------------------------
// GEMM3: 64x128 tile; A and B both via global_load_lds (A: roll(+3) gather
// with inverse-swizzled source; B: pre-swizzled W3). fp32 direct stores.
// ---------------------------------------------------------------------------
__global__ __launch_bounds__(256, 3)
void k_gemm_out(const unsigned short* __restrict__ A, const unsigned short* __restrict__ W3,
                const float* __restrict__ B, float* __restrict__ OUT) {
  __shared__ unsigned short Alds[64 * 128];   // 16KB
  __shared__ unsigned short Blds[16384];      // 32KB
  const int tid = threadIdx.x;
  const int bm = blockIdx.x;                  // 0..1567
  const int lane = tid & 63, wid = tid >> 6;

  {
    const char* gb = (const char*)W3 + (wid << 13) + (lane << 4);
    char* lb = (char*)Blds + (wid << 13) + (lane << 4);
#pragma unroll
    for (int r = 0; r < 8; ++r) gload_lds16(gb + (r << 10), lb + (r << 10));
  }
#pragma unroll
  for (int c = 0; c < 4; ++c) {
    const int ofs = (wid << 12) + (c << 10) + (lane << 4);   // linear LDS dest byte
    const int rr = ofs >> 8;
    const int colb = ofs & 255;
    const int scol = colb ^ ((rr & 7) << 4);                 // inverse swizzle on source
    const int row = bm * 64 + rr;
    const int n = row / 3136;
    const int p = row - n * 3136;
    const int rf = p / 56, cf = p - rf * 56;
    int rs = rf + 53; if (rs >= 56) rs -= 56;                // roll(+3)
    int cs = cf + 53; if (cs >= 56) cs -= 56;
    const char* ga = (const char*)A + ((size_t)(n * 3136 + rs * 56 + cs)) * 256 + scol;
    gload_lds16(ga, (char*)Alds + ofs);
  }
  __syncthreads();

  const int li = lane & 15, hi = lane >> 4;
  const int rw = (wid >> 1) << 5, cw = (wid & 1) << 6;

  f32x4 acc[2][4];
#pragma unroll
  for (int i = 0; i < 2; ++i)
#pragma unroll
    for (int j = 0; j < 4; ++j) acc[i][j] = (f32x4){0.f, 0.f, 0.f, 0.f};

#pragma unroll
  for (int kc = 0; kc < 4; ++kc) {
    s16x8 af[2], bfr[4];
#pragma unroll
    for (int i = 0; i < 2; ++i) {
      const int ra = rw + i * 16 + li;
      af[i] = *(const s16x8*)((const char*)Alds + ra * 256 + ((kc * 64 + hi * 16) ^ ((ra & 7) << 4)));
    }
#pragma unroll
    for (int j = 0; j < 4; ++j) {
      const int cb = cw + j * 16 + li;
      bfr[j] = *(const s16x8*)((const char*)Blds + cb * 256 + ((kc * 64 + hi * 16) ^ ((cb & 7) << 4)));
    }
#pragma unroll
    for (int i = 0; i < 2; ++i)
#pragma unroll
      for (int j = 0; j < 4; ++j)
        acc[i][j] = MFMA16(af[i], bfr[j], acc[i][j]);
  }

  float bias4[4];
#pragma unroll
  for (int j = 0; j < 4; ++j) bias4[j] = B[cw + j * 16 + li];
#pragma unroll
  for (int i = 0; i < 2; ++i)
#pragma unroll
    for (int r = 0; r < 4; ++r) {
      const int row = bm * 64 + rw + i * 16 + hi * 4 + r;
      float* orow = OUT + (size_t)row * 128;
#pragma unroll
      for (int j = 0; j < 4; ++j)
        orow[cw + j * 16 + li] = acc[i][j][r] + bias4[j];
    }
}

extern "C" void kernel_launch(void* const* d_in, const int* in_sizes, int n_in,
                              void* d_out, int out_size, void* d_ws, size_t ws_size,
                              hipStream_t stream) {
  const float* x = (const float*)d_in[0];
  const float* qkv_w = (const float*)d_in[1];
  const float* qkv_b = (const float*)d_in[2];
  const float* out_w = (const float*)d_in[3];
  const float* out_b = (const float*)d_in[4];
  const float* rpe = (const float*)d_in[5];
  float* out = (float*)d_out;

  unsigned short* aout = (unsigned short*)d_ws;            // 1 plane (25.7 MB)
  unsigned short* W2 = aout + PLANE;                       // 3*16384 bf16
  unsigned short* W3 = W2 + 3 * 16384;                     // 16384 bf16
  float* BIASA = (float*)(W3 + 16384);                     // 4*4096 f32

  k_prep<<<36, 256, 0, stream>>>(qkv_w, out_w, rpe, W2, W3, BIASA);
  k_fused<<<2048, 256, 0, stream>>>(x, W2, qkv_b, BIASA, aout);
  k_gemm_out<<<1568, 256, 0, stream>>>(aout, W3, out_b, out);
}

// Round 7
// 71.881 us; speedup vs baseline: 1.5793x; 1.0795x over previous
//
#include <hip/hip_runtime.h>
#include <hip/hip_bf16.h>

typedef __attribute__((ext_vector_type(4))) float f32x4;
typedef __attribute__((ext_vector_type(8))) short s16x8;
typedef __attribute__((ext_vector_type(4))) short s16x4;

#define MFMA16(a, b, c) __builtin_amdgcn_mfma_f32_16x16x32_bf16(a, b, c, 0, 0, 0)

#define PLANE ((size_t)12845056)
#define QSCALE 0.17677669529663687f

__device__ __forceinline__ unsigned short f2bf(float f) {
  union { float f; unsigned u; } v; v.f = f;
  unsigned u = v.u;
  u += 0x7fff + ((u >> 16) & 1);   // RNE
  return (unsigned short)(u >> 16);
}

typedef const __attribute__((address_space(1))) char gas_char;
typedef __attribute__((address_space(3))) char las_char;
__device__ __forceinline__ void gload_lds16(const void* g, void* l) {
  __builtin_amdgcn_global_load_lds((gas_char*)g, (las_char*)l, 16, 0, 0);
}

// ---------------------------------------------------------------------------
// Prepass.  W2/W3 stored with the PERMUTED-column mapping: storage row sr
// holds logical weight column c2 = (sr&64) + (sr&15)*4 + ((sr>>4)&3), rows
// XOR-pre-swizzled.  With this, MFMA tile j / lane li computes logical col
// cw + li*4 + j  ->  each lane's 4 tile-outputs are CONSECUTIVE columns.
// BIASA baked in MFMA C layout with k = (lane&15)*4 + (ij&3).
// ---------------------------------------------------------------------------
__global__ void k_prep(const float* __restrict__ QW, const float* __restrict__ OW,
                       const float* __restrict__ RPE,
                       unsigned short* __restrict__ W2, unsigned short* __restrict__ W3,
                       float* __restrict__ BIASA) {
  const int b = blockIdx.x, t = threadIdx.x;
  if (b < 24) {                       // qkv_w: 3*128*128
    const int e = (b * 256 + t) * 8;
    const int s = e >> 14;
    const int sr = (e & 16383) >> 7;
    const int k0 = e & 127;
    const int c2 = (sr & 64) + (sr & 15) * 4 + ((sr >> 4) & 3);
    const float sf = (s == 0) ? QSCALE : 1.0f;
    const float* src = QW + (size_t)(c2 * 3 + s) * 128 + k0;
    s16x8 h;
#pragma unroll
    for (int q = 0; q < 8; ++q) ((short*)&h)[q] = (short)f2bf(src[q] * sf);
    *(s16x8*)((char*)(W2 + (size_t)s * 16384 + sr * 128) + ((k0 * 2) ^ ((sr & 7) << 4))) = h;
  } else if (b < 32) {                // out_w: 128*128
    const int e = ((b - 24) * 256 + t) * 8;
    const int sr = e >> 7;
    const int k0 = e & 127;
    const int c2 = (sr & 64) + (sr & 15) * 4 + ((sr >> 4) & 3);
    const float* src = OW + (size_t)c2 * 128 + k0;
    s16x8 h;
#pragma unroll
    for (int q = 0; q < 8; ++q) ((short*)&h)[q] = (short)f2bf(src[q]);
    *(s16x8*)((char*)(W3 + sr * 128) + ((k0 * 2) ^ ((sr & 7) << 4))) = h;
  } else {                            // bias tables in acc-fragment layout
    const int cl = b - 32;
    const int rm = cl >> 1, cm = cl & 1;
    for (int w = 0; w < 16; ++w) {
      const int idx = w * 256 + t;       // ((i*4+j)*64 + lane)*4 + rr
      const int rr = idx & 3;
      const int lane = (idx >> 2) & 63;
      const int ij = idx >> 8;
      const int q = (ij >> 2) * 16 + ((lane >> 4) & 3) * 4 + rr;
      const int k = (lane & 15) * 4 + (ij & 3);       // permuted-k mapping
      float v;
      if (q >= 49 || k >= 49) v = -1.0e30f;
      else {
        const int xq = q / 7, yq = q - xq * 7;
        const int xk = k / 7, yk = k - xk * 7;
        v = RPE[(xk - xq + 6) * 13 + (yk - yq + 6)];
        if (rm && ((xq >= 4) != (xk >= 4))) v = -1.0e30f;
        if (cm && (((yq == 4) && (yk < 4)) || ((yq < 4) && (yk >= 4)))) v = -1.0e30f;
      }
      BIASA[cl * 4096 + idx] = v;
    }
  }
}

// ---------------------------------------------------------------------------
// FUSED gemm_qkv + attention.  Block bm: n=bm/64, wb=bm%64 -> p-rows
// [49wb,49wb+49) == windows [4wb,4wb+4) exactly.  3 weight passes write Q/K/V
// to LDS (b64 packed epilogues via the permuted-col trick); each wave then
// runs one window: QK^T with permuted-K B-operand (P-writes b64), softmax row
// sums via an all-ones MFMA B-tile (no shuffles), PV with d=li*2+fn V layout
// (conflict-free gather, packed u32 O-stores).
// ---------------------------------------------------------------------------
#define Q_OFF 0
#define K_OFF 16384
#define V_OFF 32768
#define WB_OFF 49152

__global__ __launch_bounds__(256, 2)
void k_fused(const float* __restrict__ X, const unsigned short* __restrict__ W2,
             const float* __restrict__ B, const float* __restrict__ BIASA,
             unsigned short* __restrict__ AOUT) {
  __shared__ alignas(16) char LDS[81920];
  const int tid = threadIdx.x;
  const int bm = blockIdx.x;               // 0..2047
  const int n = bm >> 6;
  const int wb = bm & 63;
  const int p0 = wb * 49;
  const int lane = tid & 63, wid = tid >> 6;
  const int li = lane & 15, hi = lane >> 4;
  const int rw = (wid >> 1) << 5;   // 0 or 32
  const int cw = (wid & 1) << 6;    // 0 or 64

  // issue B(Q) async into WB
  {
    const char* gb = (const char*)W2 + (wid << 13) + (lane << 4);
    char* lb = LDS + WB_OFF + (wid << 13) + (lane << 4);
#pragma unroll
    for (int r = 0; r < 8; ++r) gload_lds16(gb + (r << 10), lb + (r << 10));
  }

  // bias for all 3 planes at the PERMUTED logical cols cw + li*4 + j
  float bias[3][4];
#pragma unroll
  for (int s = 0; s < 3; ++s)
#pragma unroll
    for (int j = 0; j < 4; ++j)
      bias[s][j] = B[(cw + li * 4 + j) * 3 + s] * ((s == 0) ? QSCALE : 1.0f);

  // A-fragments direct from global, converted in-register
  s16x8 af[4][2];   // [kc][i]
#pragma unroll
  for (int i = 0; i < 2; ++i) {
    int p = p0 + rw + i * 16 + li;
    if (p > 3135) p = 3135;                    // pad rows (unused downstream)
    const int r_ = p / 56, c_ = p - r_ * 56;
    int ro = r_ + 4; if (ro >= 56) ro -= 56;   // roll(-4)
    int co = c_ + 4; if (co >= 56) co -= 56;
    const float* src = X + (((size_t)n * 3136 + ro * 56 + co) << 7) + hi * 8;
#pragma unroll
    for (int kc = 0; kc < 4; ++kc) {
      const f32x4 v0 = *(const f32x4*)(src + kc * 32);
      const f32x4 v1 = *(const f32x4*)(src + kc * 32 + 4);
      s16x8 h;
      h[0] = (short)f2bf(v0.x); h[1] = (short)f2bf(v0.y);
      h[2] = (short)f2bf(v0.z); h[3] = (short)f2bf(v0.w);
      h[4] = (short)f2bf(v1.x); h[5] = (short)f2bf(v1.y);
      h[6] = (short)f2bf(v1.z); h[7] = (short)f2bf(v1.w);
      af[kc][i] = h;
    }
  }
  __syncthreads();                  // B(Q) landed

#define FUSED_PASS(DST, S)                                                      \
  {                                                                             \
    f32x4 acc[2][4];                                                            \
    _Pragma("unroll")                                                           \
    for (int i = 0; i < 2; ++i)                                                 \
      _Pragma("unroll")                                                         \
      for (int j = 0; j < 4; ++j) acc[i][j] = (f32x4){0.f, 0.f, 0.f, 0.f};      \
    _Pragma("unroll")                                                           \
    for (int kc = 0; kc < 4; ++kc) {                                            \
      s16x8 bfr[4];                                                             \
      _Pragma("unroll")                                                         \
      for (int j = 0; j < 4; ++j) {                                             \
        const int cb = cw + j * 16 + li;                                        \
        bfr[j] = *(const s16x8*)(LDS + WB_OFF + cb * 256 +                      \
                                 ((kc * 64 + hi * 16) ^ ((cb & 7) << 4)));      \
      }                                                                         \
      _Pragma("unroll")                                                         \
      for (int i = 0; i < 2; ++i)                                               \
        _Pragma("unroll")                                                       \
        for (int j = 0; j < 4; ++j)                                             \
          acc[i][j] = MFMA16(af[kc][i], bfr[j], acc[i][j]);                     \
    }                                                                           \
    _Pragma("unroll")                                                           \
    for (int i = 0; i < 2; ++i)                                                 \
      _Pragma("unroll")                                                         \
      for (int r = 0; r < 4; ++r) {                                             \
        const int row = rw + i * 16 + hi * 4 + r;                               \
        s16x4 h;                                                                \
        _Pragma("unroll")                                                       \
        for (int j = 0; j < 4; ++j)                                             \
          h[j] = (short)f2bf(acc[i][j][r] + bias[S][j]);                        \
        *(s16x4*)(LDS + (DST) + row * 256 +                                     \
                  ((cw * 2 + li * 8) ^ ((row & 7) << 4))) = h;                  \
      }                                                                         \
  }

  FUSED_PASS(Q_OFF, 0)
  __syncthreads();                  // everyone done reading WB(Q)
  {
    const char* gb = (const char*)W2 + 32768 + (wid << 13) + (lane << 4);
    char* lb = LDS + WB_OFF + (wid << 13) + (lane << 4);
#pragma unroll
    for (int r = 0; r < 8; ++r) gload_lds16(gb + (r << 10), lb + (r << 10));
  }
  __syncthreads();                  // B(K) landed
  FUSED_PASS(K_OFF, 1)
  __syncthreads();
  {
    const char* gb = (const char*)W2 + 65536 + (wid << 13) + (lane << 4);
    char* lb = LDS + WB_OFF + (wid << 13) + (lane << 4);
#pragma unroll
    for (int r = 0; r < 8; ++r) gload_lds16(gb + (r << 10), lb + (r << 10));
  }
  __syncthreads();                  // B(V) landed
  FUSED_PASS(V_OFF, 2)
  __syncthreads();                  // Q/K/V staged; WB region becomes P
#undef FUSED_PASS

  // ------------------------- attention (per wave) -------------------------
  const int g = wb * 4 + wid;              // window index within n, 0..255
  const int wh = (g >> 3) & 7;
  const int ww = g & 7;
  const int cl = (wh == 7 ? 2 : 0) + (ww == 7 ? 1 : 0);
  const f32x4* bptr = (const f32x4*)(BIASA + (size_t)cl * 4096) + lane;
  char* Pw = LDS + WB_OFF + wid * 8192;    // wave-private P
  const int uw = wid * 49;                 // wave's base u within block tile

  // Q fragments (A-operand, natural rows) / K fragments (B-operand, PERMUTED:
  // tile t col li <-> k = li*4 + t)
  s16x8 qf[4], kf[4];
#pragma unroll
  for (int i = 0; i < 4; ++i) {
    const int uq = uw + i * 16 + li;
    const int pq = uq >> 2, cgq = uq & 3;
    qf[i] = *(const s16x8*)(LDS + Q_OFF + pq * 256 + ((cgq * 64 + hi * 16) ^ ((pq & 7) << 4)));
    const int uk = uw + li * 4 + i;
    const int pk = uk >> 2, cgk = uk & 3;
    kf[i] = *(const s16x8*)(LDS + K_OFF + pk * 256 + ((cgk * 64 + hi * 16) ^ ((pk & 7) << 4)));
  }

  f32x4 sc[4][4];
#pragma unroll
  for (int i = 0; i < 4; ++i)
#pragma unroll
    for (int j = 0; j < 4; ++j) sc[i][j] = bptr[(i * 4 + j) * 64];
#pragma unroll
  for (int i = 0; i < 4; ++i)
#pragma unroll
    for (int j = 0; j < 4; ++j)
      sc[i][j] = MFMA16(qf[i], kf[j], sc[i][j]);   // logits incl. bias+mask

  // softmax numerators -> P (packed b64 writes, natural [q][k] layout)
#pragma unroll
  for (int i = 0; i < 4; ++i) {
#pragma unroll
    for (int r = 0; r < 4; ++r) {
      const int q = i * 16 + hi * 4 + r;
      s16x4 pb;
#pragma unroll
      for (int j = 0; j < 4; ++j)
        pb[j] = (short)f2bf(__expf(sc[i][j][r]));
      *(s16x4*)(Pw + q * 128 + ((li * 8) ^ ((q & 7) << 4))) = pb;
    }
  }

  // V^T fragments: tile fn col li <-> d = li*2 + fn (conflict-free gather)
  s16x8 vf[2][2];
#pragma unroll
  for (int kc = 0; kc < 2; ++kc)
#pragma unroll
    for (int fn = 0; fn < 2; ++fn) {
      s16x8 tv;
#pragma unroll
      for (int jj = 0; jj < 8; ++jj) {
        const int u = uw + kc * 32 + hi * 8 + jj;
        const int p = u >> 2, cg = u & 3;
        tv[jj] = *(const short*)(LDS + V_OFF + p * 256 + ((cg * 64 + li * 4 + fn * 2) ^ ((p & 7) << 4)));
      }
      vf[kc][fn] = tv;
    }

  s16x8 ones;
#pragma unroll
  for (int e = 0; e < 8; ++e) ones[e] = (short)0x3F80;   // bf16 1.0

  const f32x4 zf = (f32x4){0.f, 0.f, 0.f, 0.f};
  f32x4 o[4][2], osum[4];
#pragma unroll
  for (int i = 0; i < 4; ++i) { o[i][0] = zf; o[i][1] = zf; osum[i] = zf; }
#pragma unroll
  for (int i = 0; i < 4; ++i) {
    const int row = i * 16 + li;
#pragma unroll
    for (int kc = 0; kc < 2; ++kc) {
      const s16x8 pf = *(const s16x8*)(Pw + row * 128 + ((kc * 64 + hi * 16) ^ ((row & 7) << 4)));
      o[i][0] = MFMA16(pf, vf[kc][0], o[i][0]);
      o[i][1] = MFMA16(pf, vf[kc][1], o[i][1]);
      osum[i] = MFMA16(pf, ones, osum[i]);       // row sums, every lane
    }
  }

  unsigned short* obase = AOUT + (((size_t)(n * 12544 + g * 49)) << 5);
#pragma unroll
  for (int i = 0; i < 4; ++i)
#pragma unroll
    for (int r = 0; r < 4; ++r) {
      const int q = i * 16 + hi * 4 + r;
      if (q < 49) {
        const float ri = 1.0f / osum[i][r];
        const unsigned lo = f2bf(o[i][0][r] * ri);          // d = li*2
        const unsigned hh = f2bf(o[i][1][r] * ri);          // d = li*2+1
        *(unsigned*)((char*)obase + q * 64 + li * 4) = lo | (hh << 16);
      }
    }
}

// ---------------------------------------------------------------------------
// GEMM3: 64x128 tile; A and B via global_load_lds; permuted W3 -> f32x4
// coalesced output stores.
// ---------------------------------------------------------------------------
__global__ __launch_bounds__(256, 3)
void k_gemm_out(const unsigned short* __restrict__ A, const unsigned short* __restrict__ W3,
                const float* __restrict__ B, float* __restrict__ OUT) {
  __shared__ unsigned short Alds[64 * 128];   // 16KB
  __shared__ unsigned short Blds[16384];      // 32KB
  const int tid = threadIdx.x;
  const int bm = blockIdx.x;                  // 0..1567
  const int lane = tid & 63, wid = tid >> 6;

  {
    const char* gb = (const char*)W3 + (wid << 13) + (lane << 4);
    char* lb = (char*)Blds + (wid << 13) + (lane << 4);
#pragma unroll
    for (int r = 0; r < 8; ++r) gload_lds16(gb + (r << 10), lb + (r << 10));
  }
#pragma unroll
  for (int c = 0; c < 4; ++c) {
    const int ofs = (wid << 12) + (c << 10) + (lane << 4);   // linear LDS dest byte
    const int rr = ofs >> 8;
    const int colb = ofs & 255;
    const int scol = colb ^ ((rr & 7) << 4);                 // inverse swizzle on source
    const int row = bm * 64 + rr;
    const int n = row / 3136;
    const int p = row - n * 3136;
    const int rf = p / 56, cf = p - rf * 56;
    int rs = rf + 53; if (rs >= 56) rs -= 56;                // roll(+3)
    int cs = cf + 53; if (cs >= 56) cs -= 56;
    const char* ga = (const char*)A + ((size_t)(n * 3136 + rs * 56 + cs)) * 256 + scol;
    gload_lds16(ga, (char*)Alds + ofs);
  }
  __syncthreads();

  const int li = lane & 15, hi = lane >> 4;
  const int rw = (wid >> 1) << 5, cw = (wid & 1) << 6;

  f32x4 acc[2][4];
#pragma unroll
  for (int i = 0; i < 2; ++i)
#pragma unroll
    for (int j = 0; j < 4; ++j) acc[i][j] = (f32x4){0.f, 0.f, 0.f, 0.f};

#pragma unroll
  for (int kc = 0; kc < 4; ++kc) {
    s16x8 af[2], bfr[4];
#pragma unroll
    for (int i = 0; i < 2; ++i) {
      const int ra = rw + i * 16 + li;
      af[i] = *(const s16x8*)((const char*)Alds + ra * 256 + ((kc * 64 + hi * 16) ^ ((ra & 7) << 4)));
    }
#pragma unroll
    for (int j = 0; j < 4; ++j) {
      const int cb = cw + j * 16 + li;
      bfr[j] = *(const s16x8*)((const char*)Blds + cb * 256 + ((kc * 64 + hi * 16) ^ ((cb & 7) << 4)));
    }
#pragma unroll
    for (int i = 0; i < 2; ++i)
#pragma unroll
      for (int j = 0; j < 4; ++j)
        acc[i][j] = MFMA16(af[i], bfr[j], acc[i][j]);
  }

  float bias4[4];
#pragma unroll
  for (int j = 0; j < 4; ++j) bias4[j] = B[cw + li * 4 + j];   // permuted cols
#pragma unroll
  for (int i = 0; i < 2; ++i)
#pragma unroll
    for (int r = 0; r < 4; ++r) {
      const int row = bm * 64 + rw + i * 16 + hi * 4 + r;
      f32x4 v;
#pragma unroll
      for (int j = 0; j < 4; ++j) v[j] = acc[i][j][r] + bias4[j];
      *(f32x4*)(OUT + (size_t)row * 128 + cw + li * 4) = v;
    }
}

extern "C" void kernel_launch(void* const* d_in, const int* in_sizes, int n_in,
                              void* d_out, int out_size, void* d_ws, size_t ws_size,
                              hipStream_t stream) {
  const float* x = (const float*)d_in[0];
  const float* qkv_w = (const float*)d_in[1];
  const float* qkv_b = (const float*)d_in[2];
  const float* out_w = (const float*)d_in[3];
  const float* out_b = (const float*)d_in[4];
  const float* rpe = (const float*)d_in[5];
  float* out = (float*)d_out;

  unsigned short* aout = (unsigned short*)d_ws;            // 1 plane (25.7 MB)
  unsigned short* W2 = aout + PLANE;                       // 3*16384 bf16
  unsigned short* W3 = W2 + 3 * 16384;                     // 16384 bf16
  float* BIASA = (float*)(W3 + 16384);                     // 4*4096 f32

  k_prep<<<36, 256, 0, stream>>>(qkv_w, out_w, rpe, W2, W3, BIASA);
  k_fused<<<2048, 256, 0, stream>>>(x, W2, qkv_b, BIASA, aout);
  k_gemm_out<<<1568, 256, 0, stream>>>(aout, W3, out_b, out);
}